// Round 1
// baseline (2442.823 us; speedup 1.0000x reference)
//
#include <hip/hip_runtime.h>

#define BB 2
#define CIN 64
#define FD 257
#define TD 500
#define FT (FD*TD)      // 128500
#define EPS 1e-5f

// ---------------------------------------------------------------------------
// Stage 1: fused fqkv (48ch) + tqk (32ch) 1x1 conv + folded BN + PReLU.
// grid = BB * 502 blocks of 256. Wave = 64 lanes x 4 contiguous cols; 4 waves
// per block each own 20 output channels. Weights broadcast from LDS.
// fq layout [b][48][f][t], tq layout [b][32][f][t].
// ---------------------------------------------------------------------------
__global__ __launch_bounds__(256) void stage1_kernel(
    const float* __restrict__ x,
    const float* __restrict__ fw, const float* __restrict__ fb_,
    const float* __restrict__ fg, const float* __restrict__ fbe,
    const float* __restrict__ fm, const float* __restrict__ fv_,
    const float* __restrict__ fa,
    const float* __restrict__ tw, const float* __restrict__ tb_,
    const float* __restrict__ tg, const float* __restrict__ tbe,
    const float* __restrict__ tm, const float* __restrict__ tv_,
    const float* __restrict__ ta,
    float* __restrict__ fq, float* __restrict__ tq)
{
    __shared__ float Wl[80*64];
    __shared__ float Bl[80];
    const int tid = threadIdx.x;
    for (int idx = tid; idx < 80*64; idx += 256) {
        const int o = idx >> 6, i = idx & 63;
        float sc, wv;
        if (o < 48) { sc = fg[o]*rsqrtf(fv_[o]+EPS); wv = fw[o*64+i]; }
        else { const int o2 = o-48; sc = tg[o2]*rsqrtf(tv_[o2]+EPS); wv = tw[o2*64+i]; }
        Wl[idx] = wv*sc;
    }
    if (tid < 80) {
        const int o = tid;
        if (o < 48) Bl[o] = (fb_[o]-fm[o])*(fg[o]*rsqrtf(fv_[o]+EPS)) + fbe[o];
        else { const int o2 = o-48; Bl[o] = (tb_[o2]-tm[o2])*(tg[o2]*rsqrtf(tv_[o2]+EPS)) + tbe[o2]; }
    }
    __syncthreads();
    const float af = fa[0], at = ta[0];
    const int og = tid >> 6, lane = tid & 63;
    const int b  = blockIdx.x / 502;
    const int nb = blockIdx.x % 502;
    const long n0 = (long)nb*256 + lane*4;
    if (n0 >= FT) return;          // FT%4==0 so tails are all-or-nothing

    float4 acc[20];
    #pragma unroll
    for (int j = 0; j < 20; ++j) {
        const float bv = Bl[og*20+j];
        acc[j] = make_float4(bv, bv, bv, bv);
    }
    const float* xb = x + (long)b*CIN*FT + n0;
    #pragma unroll 4
    for (int i = 0; i < 64; ++i) {
        const float4 xv = *(const float4*)(xb + (long)i*FT);
        #pragma unroll
        for (int j = 0; j < 20; ++j) {
            const float wv = Wl[(og*20+j)*64 + i];
            acc[j].x += wv*xv.x; acc[j].y += wv*xv.y;
            acc[j].z += wv*xv.z; acc[j].w += wv*xv.w;
        }
    }
    #pragma unroll
    for (int j = 0; j < 20; ++j) {
        const int o = og*20 + j;
        const float a_ = (o < 48) ? af : at;
        float4 v = acc[j];
        v.x = v.x >= 0.f ? v.x : a_*v.x;
        v.y = v.y >= 0.f ? v.y : a_*v.y;
        v.z = v.z >= 0.f ? v.z : a_*v.z;
        v.w = v.w >= 0.f ? v.w : a_*v.w;
        float* dst = (o < 48) ? (fq + ((long)b*48 + o)*FT + n0)
                              : (tq + ((long)b*32 + (o-48))*FT + n0);
        *(float4*)dst = v;
    }
}

// ---------------------------------------------------------------------------
// Stage 2: frequency attention. One block per (b,t). Q/K/V 16x257 in LDS.
// Wave-per-row: 64 lanes cover y=lane+64k; shuffle softmax; PV with lane=(c,q).
// Channel mapping from reshape (b,16,3,f,t): q=3c, k=3c+1, v=3c+2.
// ---------------------------------------------------------------------------
__global__ __launch_bounds__(256) void fattn_kernel(
    const float* __restrict__ fq, float* __restrict__ fo)
{
    __shared__ float Qs[16][257];
    __shared__ float Ks[16][257];
    __shared__ float Vs[16][257];
    __shared__ float prow[4][257];
    const int tid = threadIdx.x;
    const int b = blockIdx.x / TD, t = blockIdx.x % TD;
    const float* base = fq + (long)b*48*FT + t;
    for (int idx = tid; idx < 48*257; idx += 256) {
        const int c   = idx / (3*257);
        const int rem = idx - c*(3*257);
        const int w3  = rem / 257;
        const int f   = rem - w3*257;
        const float v = base[(long)(c*3 + w3)*FT + (long)f*TD];
        if (w3 == 0)      Qs[c][f] = v*0.25f;   // fold 1/sqrt(16)
        else if (w3 == 1) Ks[c][f] = v;
        else              Vs[c][f] = v;
    }
    __syncthreads();
    const int w = tid >> 6, lane = tid & 63;
    const int c = lane >> 2, q = lane & 3;
    for (int f0 = w; f0 < FD; f0 += 4) {
        float sv[5];
        float mx = -3.0e38f;
        #pragma unroll
        for (int k = 0; k < 5; ++k) {
            const int y = lane + 64*k;
            float acc = -3.0e38f;
            if (y < FD) {
                acc = 0.f;
                #pragma unroll
                for (int cc = 0; cc < 16; ++cc) acc += Qs[cc][f0]*Ks[cc][y];
            }
            sv[k] = acc;
            mx = fmaxf(mx, acc);
        }
        #pragma unroll
        for (int off = 32; off > 0; off >>= 1) mx = fmaxf(mx, __shfl_xor(mx, off, 64));
        float sum = 0.f;
        #pragma unroll
        for (int k = 0; k < 5; ++k) {
            const int y = lane + 64*k;
            if (y < FD) {
                const float p = __expf(sv[k] - mx);
                prow[w][y] = p;
                sum += p;
            }
        }
        #pragma unroll
        for (int off = 32; off > 0; off >>= 1) sum += __shfl_xor(sum, off, 64);
        const float inv = 1.f/sum;
        // PV: lane = c*4+q sums y == q (mod 4); same-wave LDS ops are in-order
        float partial = 0.f;
        for (int y = q; y < FD; y += 4) partial += prow[w][y]*Vs[c][y];
        partial *= inv;
        partial += __shfl_xor(partial, 1, 64);
        partial += __shfl_xor(partial, 2, 64);
        if (q == 0) fo[((long)(b*16 + c)*FD + f0)*TD + t] = partial;
    }
}

// ---------------------------------------------------------------------------
// Stage 3: causal time attention + fused proj/BN/PReLU/residual.
// One block per (b,f). Dynamic LDS: qt,kt,f_out,t_out 16x500 each + P rows +
// folded proj weights = 140,352 B (gfx950 allows 160 KB/WG).
// Channel mapping from reshape (b,16,2,f,t): qt=2c, kt=2c+1.
// ---------------------------------------------------------------------------
__global__ __launch_bounds__(256) void tattn_proj_kernel(
    const float* __restrict__ tq, const float* __restrict__ fo,
    const float* __restrict__ x,
    const float* __restrict__ pw, const float* __restrict__ pb_,
    const float* __restrict__ pg, const float* __restrict__ pbe,
    const float* __restrict__ pm, const float* __restrict__ pv_,
    const float* __restrict__ pa,
    float* __restrict__ out)
{
    extern __shared__ float lds[];
    float* Qs   = lds;             // 16*500
    float* Ks   = Qs  + 16*TD;     // 16*500
    float* FOs  = Ks  + 16*TD;     // 16*500
    float* TOs  = FOs + 16*TD;     // 16*500
    float* prow = TOs + 16*TD;     // 4*500
    float* PW   = prow + 4*TD;     // 64*16
    float* PB   = PW + 64*16;      // 64
    const int tid = threadIdx.x;
    const int b = blockIdx.x / FD, f = blockIdx.x % FD;
    const float* qbase = tq + (long)b*32*FT + (long)f*TD;
    const float* fbase = fo + (long)b*16*FT + (long)f*TD;
    for (int idx = tid; idx < 16*TD; idx += 256) {
        const int c = idx / TD;
        const int y = idx - c*TD;
        Qs[idx]  = qbase[(long)(2*c)*FT + y]*0.25f;
        Ks[idx]  = qbase[(long)(2*c+1)*FT + y];
        FOs[idx] = fbase[(long)c*FT + y];
    }
    for (int idx = tid; idx < 64*16; idx += 256) {
        const int o = idx >> 4;
        PW[idx] = pw[idx]*(pg[o]*rsqrtf(pv_[o]+EPS));
    }
    if (tid < 64) {
        const int o = tid;
        PB[o] = (pb_[o]-pm[o])*(pg[o]*rsqrtf(pv_[o]+EPS)) + pbe[o];
    }
    __syncthreads();
    const int w = tid >> 6, lane = tid & 63;
    const int c = lane >> 2, q = lane & 3;
    for (int t = w; t < TD; t += 4) {
        const int L = t + 1;          // causal: y <= t
        float sv[8];
        float mx = -3.0e38f;
        #pragma unroll
        for (int k = 0; k < 8; ++k) {
            const int y = lane + 64*k;
            float acc = -3.0e38f;
            if (y < L) {              // whole-wave-dead k iterations skip via execz
                acc = 0.f;
                #pragma unroll
                for (int cc = 0; cc < 16; ++cc) acc += Qs[cc*TD + t]*Ks[cc*TD + y];
            }
            sv[k] = acc;
            mx = fmaxf(mx, acc);
        }
        #pragma unroll
        for (int off = 32; off > 0; off >>= 1) mx = fmaxf(mx, __shfl_xor(mx, off, 64));
        float sum = 0.f;
        #pragma unroll
        for (int k = 0; k < 8; ++k) {
            const int y = lane + 64*k;
            if (y < L) {
                const float p = __expf(sv[k] - mx);
                prow[w*TD + y] = p;
                sum += p;
            }
        }
        #pragma unroll
        for (int off = 32; off > 0; off >>= 1) sum += __shfl_xor(sum, off, 64);
        const float inv = 1.f/sum;
        float partial = 0.f;
        for (int y = q; y < L; y += 4) partial += prow[w*TD + y]*FOs[c*TD + y];
        partial *= inv;
        partial += __shfl_xor(partial, 1, 64);
        partial += __shfl_xor(partial, 2, 64);
        if (q == 0) TOs[c*TD + t] = partial;
    }
    __syncthreads();
    // proj 16->64 + BN + PReLU + residual; coalesced along t
    const float ap = pa[0];
    for (int idx = tid; idx < 64*TD; idx += 256) {
        const int o  = idx / TD;
        const int t2 = idx - o*TD;
        float acc = PB[o];
        #pragma unroll
        for (int cc = 0; cc < 16; ++cc) acc += PW[o*16+cc]*TOs[cc*TD + t2];
        acc = acc >= 0.f ? acc : ap*acc;
        const long gi = ((long)(b*64 + o)*FD + f)*TD + t2;
        out[gi] = acc + x[gi];
    }
}

extern "C" void kernel_launch(void* const* d_in, const int* in_sizes, int n_in,
                              void* d_out, int out_size, void* d_ws, size_t ws_size,
                              hipStream_t stream)
{
    const float* x     = (const float*)d_in[0];
    const float* fw    = (const float*)d_in[1];
    const float* fb_   = (const float*)d_in[2];
    const float* fg    = (const float*)d_in[3];
    const float* fbe   = (const float*)d_in[4];
    const float* fm    = (const float*)d_in[5];
    const float* fv_   = (const float*)d_in[6];
    const float* fa    = (const float*)d_in[7];
    const float* tw    = (const float*)d_in[8];
    const float* tb_   = (const float*)d_in[9];
    const float* tg    = (const float*)d_in[10];
    const float* tbe   = (const float*)d_in[11];
    const float* tm    = (const float*)d_in[12];
    const float* tv_   = (const float*)d_in[13];
    const float* ta    = (const float*)d_in[14];
    const float* pw    = (const float*)d_in[15];
    const float* pb_   = (const float*)d_in[16];
    const float* pg    = (const float*)d_in[17];
    const float* pbe   = (const float*)d_in[18];
    const float* pm    = (const float*)d_in[19];
    const float* pv_   = (const float*)d_in[20];
    const float* pa    = (const float*)d_in[21];
    float* out = (float*)d_out;

    float* fq = (float*)d_ws;                      // [2][48][257][500]
    float* fo = fq + (long)BB*48*FT;               // [2][16][257][500]
    float* tq = fo + (long)BB*16*FT;               // [2][32][257][500]
    const size_t need = ((size_t)BB*(48+16+32)*FT)*sizeof(float);
    if (ws_size < need) return;                    // fail visibly, don't corrupt

    stage1_kernel<<<dim3(BB*502), dim3(256), 0, stream>>>(
        x, fw, fb_, fg, fbe, fm, fv_, fa, tw, tb_, tg, tbe, tm, tv_, ta, fq, tq);
    fattn_kernel<<<dim3(BB*TD), dim3(256), 0, stream>>>(fq, fo);

    const int ldsb = (4*16*TD + 4*TD + 64*16 + 64)*(int)sizeof(float); // 140,352 B
    hipFuncSetAttribute(reinterpret_cast<const void*>(tattn_proj_kernel),
                        hipFuncAttributeMaxDynamicSharedMemorySize, ldsb);
    tattn_proj_kernel<<<dim3(BB*FD), dim3(256), ldsb, stream>>>(
        tq, fo, x, pw, pb_, pg, pbe, pm, pv_, pa, out);
}

// Round 2
// 953.603 us; speedup vs baseline: 2.5617x; 2.5617x over previous
//
#include <hip/hip_runtime.h>

#define BB 2
#define CIN 64
#define FD 257
#define TD 500
#define FT (FD*TD)      // 128500
#define EPS 1e-5f
#define NEGINF (-3.0e38f)

// ---------------------------------------------------------------------------
// Stage 1: fused fqkv (48ch) + tqk (32ch) 1x1 conv + folded BN + PReLU.
// (unchanged from round 1 — not yet shown to be a bottleneck)
// ---------------------------------------------------------------------------
__global__ __launch_bounds__(256) void stage1_kernel(
    const float* __restrict__ x,
    const float* __restrict__ fw, const float* __restrict__ fb_,
    const float* __restrict__ fg, const float* __restrict__ fbe,
    const float* __restrict__ fm, const float* __restrict__ fv_,
    const float* __restrict__ fa,
    const float* __restrict__ tw, const float* __restrict__ tb_,
    const float* __restrict__ tg, const float* __restrict__ tbe,
    const float* __restrict__ tm, const float* __restrict__ tv_,
    const float* __restrict__ ta,
    float* __restrict__ fq, float* __restrict__ tq)
{
    __shared__ float Wl[80*64];
    __shared__ float Bl[80];
    const int tid = threadIdx.x;
    for (int idx = tid; idx < 80*64; idx += 256) {
        const int o = idx >> 6, i = idx & 63;
        float sc, wv;
        if (o < 48) { sc = fg[o]*rsqrtf(fv_[o]+EPS); wv = fw[o*64+i]; }
        else { const int o2 = o-48; sc = tg[o2]*rsqrtf(tv_[o2]+EPS); wv = tw[o2*64+i]; }
        Wl[idx] = wv*sc;
    }
    if (tid < 80) {
        const int o = tid;
        if (o < 48) Bl[o] = (fb_[o]-fm[o])*(fg[o]*rsqrtf(fv_[o]+EPS)) + fbe[o];
        else { const int o2 = o-48; Bl[o] = (tb_[o2]-tm[o2])*(tg[o2]*rsqrtf(tv_[o2]+EPS)) + tbe[o2]; }
    }
    __syncthreads();
    const float af = fa[0], at = ta[0];
    const int og = tid >> 6, lane = tid & 63;
    const int b  = blockIdx.x / 502;
    const int nb = blockIdx.x % 502;
    const long n0 = (long)nb*256 + lane*4;
    if (n0 >= FT) return;

    float4 acc[20];
    #pragma unroll
    for (int j = 0; j < 20; ++j) {
        const float bv = Bl[og*20+j];
        acc[j] = make_float4(bv, bv, bv, bv);
    }
    const float* xb = x + (long)b*CIN*FT + n0;
    #pragma unroll 4
    for (int i = 0; i < 64; ++i) {
        const float4 xv = *(const float4*)(xb + (long)i*FT);
        #pragma unroll
        for (int j = 0; j < 20; ++j) {
            const float wv = Wl[(og*20+j)*64 + i];
            acc[j].x += wv*xv.x; acc[j].y += wv*xv.y;
            acc[j].z += wv*xv.z; acc[j].w += wv*xv.w;
        }
    }
    #pragma unroll
    for (int j = 0; j < 20; ++j) {
        const int o = og*20 + j;
        const float a_ = (o < 48) ? af : at;
        float4 v = acc[j];
        v.x = v.x >= 0.f ? v.x : a_*v.x;
        v.y = v.y >= 0.f ? v.y : a_*v.y;
        v.z = v.z >= 0.f ? v.z : a_*v.z;
        v.w = v.w >= 0.f ? v.w : a_*v.w;
        float* dst = (o < 48) ? (fq + ((long)b*48 + o)*FT + n0)
                              : (tq + ((long)b*32 + (o-48))*FT + n0);
        *(float4*)dst = v;
    }
}

// ---------------------------------------------------------------------------
// Stage 2: frequency attention. One block per (b,t), 512 threads (8 waves).
// 58 KB static LDS -> 2 blocks/CU (16 waves). All score/PV LDS traffic is
// float4 (ds_read_b128). Row stride FP=260 (pad, 16B-aligned, V/FO 2-way
// bank groups only -> free).
// ---------------------------------------------------------------------------
#define FP 260

__global__ __launch_bounds__(512) void fattn_kernel(
    const float* __restrict__ fq, float* __restrict__ fo)
{
    __shared__ float Qs[16*FP];
    __shared__ float Ks[16*FP];
    __shared__ float Vs[16*FP];
    __shared__ float prow[8*FP];
    const int tid = threadIdx.x;
    const int b = blockIdx.x / TD, t = blockIdx.x % TD;
    const float* base = fq + (long)b*48*FT + t;
    for (int idx = tid; idx < 16*FP; idx += 512) {
        const int c = idx / FP, f = idx - c*FP;
        float qv = 0.f, kv = 0.f, vv = 0.f;
        if (f < FD) {
            const long off = (long)f*TD;
            qv = base[(long)(3*c  )*FT + off]*0.25f;   // fold 1/sqrt(16)
            kv = base[(long)(3*c+1)*FT + off];
            vv = base[(long)(3*c+2)*FT + off];
        }
        Qs[idx] = qv; Ks[idx] = kv; Vs[idx] = vv;      // pads = 0
    }
    __syncthreads();
    const int w = tid >> 6, lane = tid & 63;
    const int c = lane >> 2, q = lane & 3;
    for (int f0 = w; f0 < FD; f0 += 8) {
        float qr[16];
        #pragma unroll
        for (int cc = 0; cc < 16; ++cc) qr[cc] = Qs[cc*FP + f0];
        float4 sv[2];
        float mx = NEGINF;
        #pragma unroll
        for (int k2 = 0; k2 < 2; ++k2) {
            const int y0 = 4*lane + 256*k2;
            float4 acc = {0.f,0.f,0.f,0.f};
            if (y0 < FD) {
                #pragma unroll
                for (int cc = 0; cc < 16; ++cc) {
                    const float4 kv = *(const float4*)&Ks[cc*FP + y0];
                    acc.x += qr[cc]*kv.x; acc.y += qr[cc]*kv.y;
                    acc.z += qr[cc]*kv.z; acc.w += qr[cc]*kv.w;
                }
            }
            acc.x = (y0+0 < FD) ? acc.x : NEGINF;
            acc.y = (y0+1 < FD) ? acc.y : NEGINF;
            acc.z = (y0+2 < FD) ? acc.z : NEGINF;
            acc.w = (y0+3 < FD) ? acc.w : NEGINF;
            sv[k2] = acc;
            mx = fmaxf(mx, fmaxf(fmaxf(acc.x,acc.y), fmaxf(acc.z,acc.w)));
        }
        #pragma unroll
        for (int off = 32; off > 0; off >>= 1) mx = fmaxf(mx, __shfl_xor(mx, off, 64));
        float sum = 0.f;
        #pragma unroll
        for (int k2 = 0; k2 < 2; ++k2) {
            const int y0 = 4*lane + 256*k2;
            if (y0 < FP) {
                float4 p;
                p.x = __expf(sv[k2].x - mx);
                p.y = __expf(sv[k2].y - mx);
                p.z = __expf(sv[k2].z - mx);
                p.w = __expf(sv[k2].w - mx);
                *(float4*)&prow[w*FP + y0] = p;        // masked lanes wrote exp(-inf)=0
                sum += p.x + p.y + p.z + p.w;
            }
        }
        #pragma unroll
        for (int off = 32; off > 0; off >>= 1) sum += __shfl_xor(sum, off, 64);
        const float inv = 1.f/sum;
        float4 pacc = {0.f,0.f,0.f,0.f};
        for (int y0 = 4*q; y0 < FD; y0 += 16) {
            const float4 p4 = *(const float4*)&prow[w*FP + y0];   // broadcast across c
            const float4 v4 = *(const float4*)&Vs[c*FP + y0];
            pacc.x += p4.x*v4.x; pacc.y += p4.y*v4.y;
            pacc.z += p4.z*v4.z; pacc.w += p4.w*v4.w;
        }
        float partial = (pacc.x + pacc.y + pacc.z + pacc.w)*inv;
        partial += __shfl_xor(partial, 1, 64);
        partial += __shfl_xor(partial, 2, 64);
        if (q == 0) fo[((long)(b*16 + c)*FD + f0)*TD + t] = partial;
    }
}

// ---------------------------------------------------------------------------
// Stage 3: causal time attention + fused proj/BN/PReLU/residual.
// One block per (b,f), 512 threads (8 waves). 148 KB dynamic LDS (1 block/CU).
// float4 score/PV; causal chunk skipping (nch = ceil(L/256)).
// ---------------------------------------------------------------------------
__global__ __launch_bounds__(512) void tattn_proj_kernel(
    const float* __restrict__ tq, const float* __restrict__ fo,
    const float* __restrict__ x,
    const float* __restrict__ pw, const float* __restrict__ pb_,
    const float* __restrict__ pg, const float* __restrict__ pbe,
    const float* __restrict__ pm, const float* __restrict__ pv_,
    const float* __restrict__ pa,
    float* __restrict__ out)
{
    extern __shared__ float lds[];
    float* Qs   = lds;             // 16*500
    float* Ks   = Qs  + 16*TD;     // 16*500
    float* FOs  = Ks  + 16*TD;     // 16*500
    float* TOs  = FOs + 16*TD;     // 16*500
    float* prow = TOs + 16*TD;     // 8*500
    float* PW   = prow + 8*TD;     // 64*16
    float* PB   = PW + 64*16;      // 64
    const int tid = threadIdx.x;
    const int b = blockIdx.x / FD, f = blockIdx.x % FD;
    const float* qbase = tq + (long)b*32*FT + (long)f*TD;
    const float* fbase = fo + (long)b*16*FT + (long)f*TD;
    // float4-coalesced staging: rows are contiguous along t in global
    for (int idx = tid; idx < 16*125; idx += 512) {
        const int c = idx / 125, j4 = (idx - c*125)*4;
        float4 qv = *(const float4*)(qbase + (long)(2*c  )*FT + j4);
        qv.x *= 0.25f; qv.y *= 0.25f; qv.z *= 0.25f; qv.w *= 0.25f;
        *(float4*)&Qs[c*TD + j4] = qv;
        *(float4*)&Ks[c*TD + j4]  = *(const float4*)(qbase + (long)(2*c+1)*FT + j4);
        *(float4*)&FOs[c*TD + j4] = *(const float4*)(fbase + (long)c*FT + j4);
    }
    for (int idx = tid; idx < 64*16; idx += 512) {
        const int o = idx >> 4;
        PW[idx] = pw[idx]*(pg[o]*rsqrtf(pv_[o]+EPS));
    }
    if (tid < 64) {
        const int o = tid;
        PB[o] = (pb_[o]-pm[o])*(pg[o]*rsqrtf(pv_[o]+EPS)) + pbe[o];
    }
    __syncthreads();
    const int w = tid >> 6, lane = tid & 63;
    const int c = lane >> 2, q = lane & 3;
    for (int t = w; t < TD; t += 8) {
        const int L = t + 1;                 // causal: y <= t
        float qr[16];
        #pragma unroll
        for (int cc = 0; cc < 16; ++cc) qr[cc] = Qs[cc*TD + t];
        const int nch = (L + 255) >> 8;      // 1 or 2 chunks (wave-uniform)
        float4 sv[2];
        float mx = NEGINF;
        for (int k2 = 0; k2 < nch; ++k2) {
            const int y0 = 4*lane + 256*k2;
            float4 acc = {0.f,0.f,0.f,0.f};
            if (y0 < L) {                    // inactive lanes skip LDS reads
                #pragma unroll
                for (int cc = 0; cc < 16; ++cc) {
                    const float4 kv = *(const float4*)&Ks[cc*TD + y0];
                    acc.x += qr[cc]*kv.x; acc.y += qr[cc]*kv.y;
                    acc.z += qr[cc]*kv.z; acc.w += qr[cc]*kv.w;
                }
            }
            acc.x = (y0+0 < L) ? acc.x : NEGINF;
            acc.y = (y0+1 < L) ? acc.y : NEGINF;
            acc.z = (y0+2 < L) ? acc.z : NEGINF;
            acc.w = (y0+3 < L) ? acc.w : NEGINF;
            sv[k2] = acc;
            mx = fmaxf(mx, fmaxf(fmaxf(acc.x,acc.y), fmaxf(acc.z,acc.w)));
        }
        #pragma unroll
        for (int off = 32; off > 0; off >>= 1) mx = fmaxf(mx, __shfl_xor(mx, off, 64));
        float sum = 0.f;
        for (int k2 = 0; k2 < nch; ++k2) {
            const int y0 = 4*lane + 256*k2;
            if (y0 < TD) {
                float4 p;
                p.x = __expf(sv[k2].x - mx);
                p.y = __expf(sv[k2].y - mx);
                p.z = __expf(sv[k2].z - mx);
                p.w = __expf(sv[k2].w - mx);
                *(float4*)&prow[w*TD + y0] = p;   // y>=L slots get exp(-inf)=0
                sum += p.x + p.y + p.z + p.w;
            }
        }
        #pragma unroll
        for (int off = 32; off > 0; off >>= 1) sum += __shfl_xor(sum, off, 64);
        const float inv = 1.f/sum;
        float4 pacc = {0.f,0.f,0.f,0.f};
        for (int y0 = 4*q; y0 < L; y0 += 16) {
            const float4 p4 = *(const float4*)&prow[w*TD + y0];   // broadcast across c
            const float4 f4 = *(const float4*)&FOs[c*TD + y0];
            pacc.x += p4.x*f4.x; pacc.y += p4.y*f4.y;
            pacc.z += p4.z*f4.z; pacc.w += p4.w*f4.w;
        }
        float partial = (pacc.x + pacc.y + pacc.z + pacc.w)*inv;
        partial += __shfl_xor(partial, 1, 64);
        partial += __shfl_xor(partial, 2, 64);
        if (q == 0) TOs[c*TD + t] = partial;
    }
    __syncthreads();
    // proj 16->64 + BN + PReLU + residual; coalesced along t
    const float ap = pa[0];
    for (int idx = tid; idx < 64*TD; idx += 512) {
        const int o  = idx / TD;
        const int t2 = idx - o*TD;
        float acc = PB[o];
        #pragma unroll
        for (int cc = 0; cc < 16; ++cc) acc += PW[o*16+cc]*TOs[cc*TD + t2];
        acc = acc >= 0.f ? acc : ap*acc;
        const long gi = ((long)(b*64 + o)*FD + f)*TD + t2;
        out[gi] = acc + x[gi];
    }
}

extern "C" void kernel_launch(void* const* d_in, const int* in_sizes, int n_in,
                              void* d_out, int out_size, void* d_ws, size_t ws_size,
                              hipStream_t stream)
{
    const float* x     = (const float*)d_in[0];
    const float* fw    = (const float*)d_in[1];
    const float* fb_   = (const float*)d_in[2];
    const float* fg    = (const float*)d_in[3];
    const float* fbe   = (const float*)d_in[4];
    const float* fm    = (const float*)d_in[5];
    const float* fv_   = (const float*)d_in[6];
    const float* fa    = (const float*)d_in[7];
    const float* tw    = (const float*)d_in[8];
    const float* tb_   = (const float*)d_in[9];
    const float* tg    = (const float*)d_in[10];
    const float* tbe   = (const float*)d_in[11];
    const float* tm    = (const float*)d_in[12];
    const float* tv_   = (const float*)d_in[13];
    const float* ta    = (const float*)d_in[14];
    const float* pw    = (const float*)d_in[15];
    const float* pb_   = (const float*)d_in[16];
    const float* pg    = (const float*)d_in[17];
    const float* pbe   = (const float*)d_in[18];
    const float* pm    = (const float*)d_in[19];
    const float* pv_   = (const float*)d_in[20];
    const float* pa    = (const float*)d_in[21];
    float* out = (float*)d_out;

    float* fq = (float*)d_ws;                      // [2][48][257][500]
    float* fo = fq + (long)BB*48*FT;               // [2][16][257][500]
    float* tq = fo + (long)BB*16*FT;               // [2][32][257][500]
    const size_t need = ((size_t)BB*(48+16+32)*FT)*sizeof(float);
    if (ws_size < need) return;

    stage1_kernel<<<dim3(BB*502), dim3(256), 0, stream>>>(
        x, fw, fb_, fg, fbe, fm, fv_, fa, tw, tb_, tg, tbe, tm, tv_, ta, fq, tq);
    fattn_kernel<<<dim3(BB*TD), dim3(512), 0, stream>>>(fq, fo);

    const int ldsb = (4*16*TD + 8*TD + 64*16 + 64)*(int)sizeof(float); // 148,352 B
    hipFuncSetAttribute(reinterpret_cast<const void*>(tattn_proj_kernel),
                        hipFuncAttributeMaxDynamicSharedMemorySize, ldsb);
    tattn_proj_kernel<<<dim3(BB*FD), dim3(512), ldsb, stream>>>(
        tq, fo, x, pw, pb_, pg, pbe, pm, pv_, pa, out);
}

// Round 3
// 842.875 us; speedup vs baseline: 2.8982x; 1.1314x over previous
//
#include <hip/hip_runtime.h>

#define BB 2
#define CIN 64
#define FD 257
#define TD 500
#define FT (FD*TD)      // 128500
#define EPS 1e-5f
#define NEGINF (-3.0e38f)
#define TDP 512         // padded t-tile row stride (tattn)
#define FP2 264         // padded f-tile row stride (fattn)

// ---------------------------------------------------------------------------
// Stage 1: fused fqkv (48ch) + tqk (32ch) 1x1 conv + folded BN + PReLU.
// ---------------------------------------------------------------------------
__global__ __launch_bounds__(256) void stage1_kernel(
    const float* __restrict__ x,
    const float* __restrict__ fw, const float* __restrict__ fb_,
    const float* __restrict__ fg, const float* __restrict__ fbe,
    const float* __restrict__ fm, const float* __restrict__ fv_,
    const float* __restrict__ fa,
    const float* __restrict__ tw, const float* __restrict__ tb_,
    const float* __restrict__ tg, const float* __restrict__ tbe,
    const float* __restrict__ tm, const float* __restrict__ tv_,
    const float* __restrict__ ta,
    float* __restrict__ fq, float* __restrict__ tq)
{
    __shared__ float Wl[80*64];
    __shared__ float Bl[80];
    const int tid = threadIdx.x;
    for (int idx = tid; idx < 80*64; idx += 256) {
        const int o = idx >> 6, i = idx & 63;
        float sc, wv;
        if (o < 48) { sc = fg[o]*rsqrtf(fv_[o]+EPS); wv = fw[o*64+i]; }
        else { const int o2 = o-48; sc = tg[o2]*rsqrtf(tv_[o2]+EPS); wv = tw[o2*64+i]; }
        Wl[idx] = wv*sc;
    }
    if (tid < 80) {
        const int o = tid;
        if (o < 48) Bl[o] = (fb_[o]-fm[o])*(fg[o]*rsqrtf(fv_[o]+EPS)) + fbe[o];
        else { const int o2 = o-48; Bl[o] = (tb_[o2]-tm[o2])*(tg[o2]*rsqrtf(tv_[o2]+EPS)) + tbe[o2]; }
    }
    __syncthreads();
    const float af = fa[0], at = ta[0];
    const int og = tid >> 6, lane = tid & 63;
    const int b  = blockIdx.x / 502;
    const int nb = blockIdx.x % 502;
    const long n0 = (long)nb*256 + lane*4;
    if (n0 >= FT) return;

    float4 acc[20];
    #pragma unroll
    for (int j = 0; j < 20; ++j) {
        const float bv = Bl[og*20+j];
        acc[j] = make_float4(bv, bv, bv, bv);
    }
    const float* xb = x + (long)b*CIN*FT + n0;
    #pragma unroll 4
    for (int i = 0; i < 64; ++i) {
        const float4 xv = *(const float4*)(xb + (long)i*FT);
        #pragma unroll
        for (int j = 0; j < 20; ++j) {
            const float wv = Wl[(og*20+j)*64 + i];
            acc[j].x += wv*xv.x; acc[j].y += wv*xv.y;
            acc[j].z += wv*xv.z; acc[j].w += wv*xv.w;
        }
    }
    #pragma unroll
    for (int j = 0; j < 20; ++j) {
        const int o = og*20 + j;
        const float a_ = (o < 48) ? af : at;
        float4 v = acc[j];
        v.x = v.x >= 0.f ? v.x : a_*v.x;
        v.y = v.y >= 0.f ? v.y : a_*v.y;
        v.z = v.z >= 0.f ? v.z : a_*v.z;
        v.w = v.w >= 0.f ? v.w : a_*v.w;
        float* dst = (o < 48) ? (fq + ((long)b*48 + o)*FT + n0)
                              : (tq + ((long)b*32 + (o-48))*FT + n0);
        *(float4*)dst = v;
    }
}

// softmax row epilogue + PV, shared by both attention kernels.
// sv0/sv1 are the two 256-wide score chunks for ONE row (NEGINF-masked).
// Returns nothing; writes one output row via caller-provided store lambda-ish.
__device__ __forceinline__ float row_softmax_pv(
    float4 s0, float4 s1, float mx, int nch, int L, int boundP,
    float* __restrict__ prow_w, const float* __restrict__ Vrow_base,
    int rowStride, int c, int q, int lane)
{
    #pragma unroll
    for (int off = 32; off > 0; off >>= 1) mx = fmaxf(mx, __shfl_xor(mx, off, 64));
    float sum = 0.f;
    {
        const int y0 = 4*lane;
        float4 p;
        p.x = __expf(s0.x - mx); p.y = __expf(s0.y - mx);
        p.z = __expf(s0.z - mx); p.w = __expf(s0.w - mx);
        *(float4*)&prow_w[y0] = p;
        sum += p.x + p.y + p.z + p.w;
    }
    if (nch > 1) {
        const int y0 = 4*lane + 256;
        if (y0 < boundP) {                 // keep store inside this wave's prow row
            float4 p;
            p.x = __expf(s1.x - mx); p.y = __expf(s1.y - mx);
            p.z = __expf(s1.z - mx); p.w = __expf(s1.w - mx);
            *(float4*)&prow_w[y0] = p;
            sum += p.x + p.y + p.z + p.w;
        }
    }
    #pragma unroll
    for (int off = 32; off > 0; off >>= 1) sum += __shfl_xor(sum, off, 64);
    const float inv = 1.f/sum;
    float4 pacc = {0.f,0.f,0.f,0.f};
    for (int y0 = 4*q; y0 < L; y0 += 16) {
        const float4 p4 = *(const float4*)&prow_w[y0];
        const float4 v4 = *(const float4*)&Vrow_base[c*rowStride + y0];
        pacc.x += p4.x*v4.x; pacc.y += p4.y*v4.y;
        pacc.z += p4.z*v4.z; pacc.w += p4.w*v4.w;
    }
    float partial = (pacc.x + pacc.y + pacc.z + pacc.w)*inv;
    partial += __shfl_xor(partial, 1, 64);
    partial += __shfl_xor(partial, 2, 64);
    return partial;   // valid on q==0 lanes
}

// ---------------------------------------------------------------------------
// Stage 2: frequency attention. One block per (b,t), 1024 threads (16 waves),
// 2-row register blocking (rows f0,f0+1 share K reads). Dynamic LDS 67.6 KB.
// ---------------------------------------------------------------------------
__global__ __launch_bounds__(1024, 4) void fattn_kernel(
    const float* __restrict__ fq, float* __restrict__ fo)
{
    extern __shared__ float lds[];
    float* Qs   = lds;              // 16*FP2
    float* Ks   = Qs + 16*FP2;
    float* Vs   = Ks + 16*FP2;
    float* prow = Vs + 16*FP2;      // 16 waves * FP2
    const int tid = threadIdx.x;
    const int b = blockIdx.x / TD, t = blockIdx.x % TD;
    const float* base = fq + (long)b*48*FT + t;
    for (int idx = tid; idx < 16*FP2; idx += 1024) {
        const int c = idx / FP2, f = idx - c*FP2;
        float qv = 0.f, kv = 0.f, vv = 0.f;
        if (f < FD) {
            const long off = (long)f*TD;
            qv = base[(long)(3*c  )*FT + off]*0.25f;
            kv = base[(long)(3*c+1)*FT + off];
            vv = base[(long)(3*c+2)*FT + off];
        }
        Qs[idx] = qv; Ks[idx] = kv; Vs[idx] = vv;
    }
    __syncthreads();
    const int w = tid >> 6, lane = tid & 63;
    const int c = lane >> 2, q = lane & 3;
    float* prow_w = prow + w*FP2;
    for (int kp = 0; kp < 9; ++kp) {
        const int f0 = 32*kp + 2*w;
        if (f0 >= FD) break;
        const bool has1 = (f0+1 < FD);
        float2 q01[16];
        #pragma unroll
        for (int cc = 0; cc < 16; ++cc) q01[cc] = *(const float2*)&Qs[cc*FP2 + f0];
        float4 s00={0,0,0,0}, s01={0,0,0,0}, s10={0,0,0,0}, s11={0,0,0,0};
        {   // chunk 0: y in [0,256)
            const int y0 = 4*lane;
            #pragma unroll
            for (int cc = 0; cc < 16; ++cc) {
                const float4 kv = *(const float4*)&Ks[cc*FP2 + y0];
                s00.x += q01[cc].x*kv.x; s00.y += q01[cc].x*kv.y;
                s00.z += q01[cc].x*kv.z; s00.w += q01[cc].x*kv.w;
                s10.x += q01[cc].y*kv.x; s10.y += q01[cc].y*kv.y;
                s10.z += q01[cc].y*kv.z; s10.w += q01[cc].y*kv.w;
            }
        }
        {   // chunk 1: only y=256 valid (lane 0)
            const int y0 = 4*lane + 256;
            if (y0 < FD) {
                #pragma unroll
                for (int cc = 0; cc < 16; ++cc) {
                    const float4 kv = *(const float4*)&Ks[cc*FP2 + y0];
                    s01.x += q01[cc].x*kv.x; s01.y += q01[cc].x*kv.y;
                    s01.z += q01[cc].x*kv.z; s01.w += q01[cc].x*kv.w;
                    s11.x += q01[cc].y*kv.x; s11.y += q01[cc].y*kv.y;
                    s11.z += q01[cc].y*kv.z; s11.w += q01[cc].y*kv.w;
                }
            }
            s01.x = (y0+0 < FD) ? s01.x : NEGINF;
            s01.y = (y0+1 < FD) ? s01.y : NEGINF;
            s01.z = (y0+2 < FD) ? s01.z : NEGINF;
            s01.w = (y0+3 < FD) ? s01.w : NEGINF;
            s11.x = (y0+0 < FD) ? s11.x : NEGINF;
            s11.y = (y0+1 < FD) ? s11.y : NEGINF;
            s11.z = (y0+2 < FD) ? s11.z : NEGINF;
            s11.w = (y0+3 < FD) ? s11.w : NEGINF;
        }
        float mx0 = fmaxf(fmaxf(s00.x,s00.y), fmaxf(s00.z,s00.w));
        mx0 = fmaxf(mx0, fmaxf(fmaxf(s01.x,s01.y), fmaxf(s01.z,s01.w)));
        float p0 = row_softmax_pv(s00, s01, mx0, 2, FD, FD, prow_w, Vs, FP2, c, q, lane);
        if (q == 0) fo[((long)(b*16 + c)*FD + f0)*TD + t] = p0;
        if (has1) {
            float mx1 = fmaxf(fmaxf(s10.x,s10.y), fmaxf(s10.z,s10.w));
            mx1 = fmaxf(mx1, fmaxf(fmaxf(s11.x,s11.y), fmaxf(s11.z,s11.w)));
            float p1 = row_softmax_pv(s10, s11, mx1, 2, FD, FD, prow_w, Vs, FP2, c, q, lane);
            if (q == 0) fo[((long)(b*16 + c)*FD + f0+1)*TD + t] = p1;
        }
    }
}

// ---------------------------------------------------------------------------
// Stage 3: causal time attention. One block per (b,f), 1024 threads (16
// waves), 2-row blocking. Dynamic LDS 128 KB (Q/K/FO/prow @ 16x512 f32).
// Writes t_out [b][16][f][t] to workspace; proj is a separate kernel.
// ---------------------------------------------------------------------------
__global__ __launch_bounds__(1024, 4) void tattn_kernel(
    const float* __restrict__ tq, const float* __restrict__ fo,
    float* __restrict__ tout)
{
    extern __shared__ float lds[];
    float* Qs   = lds;              // 16*TDP
    float* Ks   = Qs  + 16*TDP;
    float* FOs  = Ks  + 16*TDP;
    float* prow = FOs + 16*TDP;     // 16 waves * TDP
    const int tid = threadIdx.x;
    const int b = blockIdx.x / FD, f = blockIdx.x % FD;
    const float* qbase = tq + (long)b*32*FT + (long)f*TD;
    const float* fbase = fo + (long)b*16*FT + (long)f*TD;
    for (int idx = tid; idx < 16*128; idx += 1024) {      // 128 float4 slots/row
        const int c = idx >> 7, j4 = (idx & 127) << 2;
        float4 qv = {0,0,0,0}, kv = {0,0,0,0}, fv = {0,0,0,0};
        if (j4 < TD) {
            qv = *(const float4*)(qbase + (long)(2*c  )*FT + j4);
            qv.x *= 0.25f; qv.y *= 0.25f; qv.z *= 0.25f; qv.w *= 0.25f;
            kv = *(const float4*)(qbase + (long)(2*c+1)*FT + j4);
            fv = *(const float4*)(fbase + (long)c*FT + j4);
        }
        *(float4*)&Qs[c*TDP + j4]  = qv;
        *(float4*)&Ks[c*TDP + j4]  = kv;
        *(float4*)&FOs[c*TDP + j4] = fv;
    }
    __syncthreads();
    const int w = tid >> 6, lane = tid & 63;
    const int c = lane >> 2, q = lane & 3;
    float* prow_w = prow + w*TDP;
    for (int kp = 0; kp < 16; ++kp) {
        const int t0 = 32*kp + 2*w;
        if (t0 >= TD) break;
        const int L0 = t0 + 1, L1 = t0 + 2;     // causal lengths, rows t0 and t0+1
        const int nch = (L1 + 255) >> 8;        // 1 or 2 (wave-uniform)
        float2 q01[16];
        #pragma unroll
        for (int cc = 0; cc < 16; ++cc) q01[cc] = *(const float2*)&Qs[cc*TDP + t0];
        float4 s00={0,0,0,0}, s01={0,0,0,0}, s10={0,0,0,0}, s11={0,0,0,0};
        {   // chunk 0
            const int y0 = 4*lane;
            if (y0 < L1) {
                #pragma unroll
                for (int cc = 0; cc < 16; ++cc) {
                    const float4 kv = *(const float4*)&Ks[cc*TDP + y0];
                    s00.x += q01[cc].x*kv.x; s00.y += q01[cc].x*kv.y;
                    s00.z += q01[cc].x*kv.z; s00.w += q01[cc].x*kv.w;
                    s10.x += q01[cc].y*kv.x; s10.y += q01[cc].y*kv.y;
                    s10.z += q01[cc].y*kv.z; s10.w += q01[cc].y*kv.w;
                }
            }
            s00.x = (y0+0 < L0) ? s00.x : NEGINF;
            s00.y = (y0+1 < L0) ? s00.y : NEGINF;
            s00.z = (y0+2 < L0) ? s00.z : NEGINF;
            s00.w = (y0+3 < L0) ? s00.w : NEGINF;
            s10.x = (y0+0 < L1) ? s10.x : NEGINF;
            s10.y = (y0+1 < L1) ? s10.y : NEGINF;
            s10.z = (y0+2 < L1) ? s10.z : NEGINF;
            s10.w = (y0+3 < L1) ? s10.w : NEGINF;
        }
        if (nch > 1) {   // chunk 1
            const int y0 = 4*lane + 256;
            if (y0 < L1) {
                #pragma unroll
                for (int cc = 0; cc < 16; ++cc) {
                    const float4 kv = *(const float4*)&Ks[cc*TDP + y0];
                    s01.x += q01[cc].x*kv.x; s01.y += q01[cc].x*kv.y;
                    s01.z += q01[cc].x*kv.z; s01.w += q01[cc].x*kv.w;
                    s11.x += q01[cc].y*kv.x; s11.y += q01[cc].y*kv.y;
                    s11.z += q01[cc].y*kv.z; s11.w += q01[cc].y*kv.w;
                }
            }
            s01.x = (y0+0 < L0) ? s01.x : NEGINF;
            s01.y = (y0+1 < L0) ? s01.y : NEGINF;
            s01.z = (y0+2 < L0) ? s01.z : NEGINF;
            s01.w = (y0+3 < L0) ? s01.w : NEGINF;
            s11.x = (y0+0 < L1) ? s11.x : NEGINF;
            s11.y = (y0+1 < L1) ? s11.y : NEGINF;
            s11.z = (y0+2 < L1) ? s11.z : NEGINF;
            s11.w = (y0+3 < L1) ? s11.w : NEGINF;
        } else {
            s01 = make_float4(NEGINF,NEGINF,NEGINF,NEGINF);
            s11 = make_float4(NEGINF,NEGINF,NEGINF,NEGINF);
        }
        float mx0 = fmaxf(fmaxf(s00.x,s00.y), fmaxf(s00.z,s00.w));
        mx0 = fmaxf(mx0, fmaxf(fmaxf(s01.x,s01.y), fmaxf(s01.z,s01.w)));
        float p0 = row_softmax_pv(s00, s01, mx0, nch, L0, TDP, prow_w, FOs, TDP, c, q, lane);
        if (q == 0) tout[((long)(b*16 + c)*FD + f)*TD + t0] = p0;
        float mx1 = fmaxf(fmaxf(s10.x,s10.y), fmaxf(s10.z,s10.w));
        mx1 = fmaxf(mx1, fmaxf(fmaxf(s11.x,s11.y), fmaxf(s11.z,s11.w)));
        float p1 = row_softmax_pv(s10, s11, mx1, nch, L1, TDP, prow_w, FOs, TDP, c, q, lane);
        if (q == 0) tout[((long)(b*16 + c)*FD + f)*TD + t0+1] = p1;
    }
}

// ---------------------------------------------------------------------------
// Stage 4: proj 16->64 + BN + PReLU + residual. Streaming GEMM, coalesced.
// grid BB*502 x 256 threads; 4 waves each own 16 out channels of a 256-col
// tile.
// ---------------------------------------------------------------------------
__global__ __launch_bounds__(256) void proj_kernel(
    const float* __restrict__ tout, const float* __restrict__ x,
    const float* __restrict__ pw, const float* __restrict__ pb_,
    const float* __restrict__ pg, const float* __restrict__ pbe,
    const float* __restrict__ pm, const float* __restrict__ pv_,
    const float* __restrict__ pa,
    float* __restrict__ out)
{
    __shared__ float PW[64*16];
    __shared__ float PB[64];
    const int tid = threadIdx.x;
    for (int idx = tid; idx < 64*16; idx += 256) {
        const int o = idx >> 4;
        PW[idx] = pw[idx]*(pg[o]*rsqrtf(pv_[o]+EPS));
    }
    if (tid < 64) {
        const int o = tid;
        PB[o] = (pb_[o]-pm[o])*(pg[o]*rsqrtf(pv_[o]+EPS)) + pbe[o];
    }
    __syncthreads();
    const float ap = pa[0];
    const int og = tid >> 6, lane = tid & 63;
    const int b  = blockIdx.x / 502;
    const int nb = blockIdx.x % 502;
    const long n0 = (long)nb*256 + lane*4;
    if (n0 >= FT) return;
    float4 acc[16];
    #pragma unroll
    for (int j = 0; j < 16; ++j) {
        const float bv = PB[og*16+j];
        acc[j] = make_float4(bv, bv, bv, bv);
    }
    const float* tb = tout + (long)b*16*FT + n0;
    #pragma unroll
    for (int cc = 0; cc < 16; ++cc) {
        const float4 tv = *(const float4*)(tb + (long)cc*FT);
        #pragma unroll
        for (int j = 0; j < 16; ++j) {
            const float wv = PW[(og*16+j)*16 + cc];
            acc[j].x += wv*tv.x; acc[j].y += wv*tv.y;
            acc[j].z += wv*tv.z; acc[j].w += wv*tv.w;
        }
    }
    #pragma unroll
    for (int j = 0; j < 16; ++j) {
        const int o = og*16 + j;
        float4 v = acc[j];
        v.x = v.x >= 0.f ? v.x : ap*v.x;
        v.y = v.y >= 0.f ? v.y : ap*v.y;
        v.z = v.z >= 0.f ? v.z : ap*v.z;
        v.w = v.w >= 0.f ? v.w : ap*v.w;
        const long gi = (long)(b*64 + o)*FT + n0;
        const float4 xv = *(const float4*)(x + gi);
        v.x += xv.x; v.y += xv.y; v.z += xv.z; v.w += xv.w;
        *(float4*)(out + gi) = v;
    }
}

extern "C" void kernel_launch(void* const* d_in, const int* in_sizes, int n_in,
                              void* d_out, int out_size, void* d_ws, size_t ws_size,
                              hipStream_t stream)
{
    const float* x     = (const float*)d_in[0];
    const float* fw    = (const float*)d_in[1];
    const float* fb_   = (const float*)d_in[2];
    const float* fg    = (const float*)d_in[3];
    const float* fbe   = (const float*)d_in[4];
    const float* fm    = (const float*)d_in[5];
    const float* fv_   = (const float*)d_in[6];
    const float* fa    = (const float*)d_in[7];
    const float* tw    = (const float*)d_in[8];
    const float* tb_   = (const float*)d_in[9];
    const float* tg    = (const float*)d_in[10];
    const float* tbe   = (const float*)d_in[11];
    const float* tm    = (const float*)d_in[12];
    const float* tv_   = (const float*)d_in[13];
    const float* ta    = (const float*)d_in[14];
    const float* pw    = (const float*)d_in[15];
    const float* pb_   = (const float*)d_in[16];
    const float* pg    = (const float*)d_in[17];
    const float* pbe   = (const float*)d_in[18];
    const float* pm    = (const float*)d_in[19];
    const float* pv_   = (const float*)d_in[20];
    const float* pa    = (const float*)d_in[21];
    float* out = (float*)d_out;

    float* fq   = (float*)d_ws;                    // [2][48][257][500]
    float* fo   = fq + (long)BB*48*FT;             // [2][16][257][500]
    float* tq   = fo + (long)BB*16*FT;             // [2][32][257][500]
    float* tout = fq;                              // alias: fq dead after fattn
    const size_t need = ((size_t)BB*(48+16+32)*FT)*sizeof(float);
    if (ws_size < need) return;

    stage1_kernel<<<dim3(BB*502), dim3(256), 0, stream>>>(
        x, fw, fb_, fg, fbe, fm, fv_, fa, tw, tb_, tg, tbe, tm, tv_, ta, fq, tq);

    const int flds = 4*16*FP2*(int)sizeof(float);  // 67,584 B
    hipFuncSetAttribute(reinterpret_cast<const void*>(fattn_kernel),
                        hipFuncAttributeMaxDynamicSharedMemorySize, flds);
    fattn_kernel<<<dim3(BB*TD), dim3(1024), flds, stream>>>(fq, fo);

    const int tlds = 4*16*TDP*(int)sizeof(float);  // 131,072 B
    hipFuncSetAttribute(reinterpret_cast<const void*>(tattn_kernel),
                        hipFuncAttributeMaxDynamicSharedMemorySize, tlds);
    tattn_kernel<<<dim3(BB*FD), dim3(1024), tlds, stream>>>(tq, fo, tout);

    proj_kernel<<<dim3(BB*502), dim3(256), 0, stream>>>(
        tout, x, pw, pb_, pg, pbe, pm, pv_, pa, out);
}

// Round 4
// 427.799 us; speedup vs baseline: 5.7102x; 1.9703x over previous
//
#include <hip/hip_runtime.h>

#define BB 2
#define CIN 64
#define FD 257
#define TD 500
#define FT (FD*TD)      // 128500
#define EPS 1e-5f
#define NEGINF (-3.0e38f)

typedef _Float16 half_t;
typedef half_t half4 __attribute__((ext_vector_type(4)));
typedef float  f32x4 __attribute__((ext_vector_type(4)));

// ---------------------------------------------------------------------------
// Stage 1: fused fqkv (48ch) + tqk (32ch) 1x1 conv + folded BN + PReLU.
// (unchanged from round 3)
// ---------------------------------------------------------------------------
__global__ __launch_bounds__(256) void stage1_kernel(
    const float* __restrict__ x,
    const float* __restrict__ fw, const float* __restrict__ fb_,
    const float* __restrict__ fg, const float* __restrict__ fbe,
    const float* __restrict__ fm, const float* __restrict__ fv_,
    const float* __restrict__ fa,
    const float* __restrict__ tw, const float* __restrict__ tb_,
    const float* __restrict__ tg, const float* __restrict__ tbe,
    const float* __restrict__ tm, const float* __restrict__ tv_,
    const float* __restrict__ ta,
    float* __restrict__ fq, float* __restrict__ tq)
{
    __shared__ float Wl[80*64];
    __shared__ float Bl[80];
    const int tid = threadIdx.x;
    for (int idx = tid; idx < 80*64; idx += 256) {
        const int o = idx >> 6, i = idx & 63;
        float sc, wv;
        if (o < 48) { sc = fg[o]*rsqrtf(fv_[o]+EPS); wv = fw[o*64+i]; }
        else { const int o2 = o-48; sc = tg[o2]*rsqrtf(tv_[o2]+EPS); wv = tw[o2*64+i]; }
        Wl[idx] = wv*sc;
    }
    if (tid < 80) {
        const int o = tid;
        if (o < 48) Bl[o] = (fb_[o]-fm[o])*(fg[o]*rsqrtf(fv_[o]+EPS)) + fbe[o];
        else { const int o2 = o-48; Bl[o] = (tb_[o2]-tm[o2])*(tg[o2]*rsqrtf(tv_[o2]+EPS)) + tbe[o2]; }
    }
    __syncthreads();
    const float af = fa[0], at = ta[0];
    const int og = tid >> 6, lane = tid & 63;
    const int b  = blockIdx.x / 502;
    const int nb = blockIdx.x % 502;
    const long n0 = (long)nb*256 + lane*4;
    if (n0 >= FT) return;

    float4 acc[20];
    #pragma unroll
    for (int j = 0; j < 20; ++j) {
        const float bv = Bl[og*20+j];
        acc[j] = make_float4(bv, bv, bv, bv);
    }
    const float* xb = x + (long)b*CIN*FT + n0;
    #pragma unroll 4
    for (int i = 0; i < 64; ++i) {
        const float4 xv = *(const float4*)(xb + (long)i*FT);
        #pragma unroll
        for (int j = 0; j < 20; ++j) {
            const float wv = Wl[(og*20+j)*64 + i];
            acc[j].x += wv*xv.x; acc[j].y += wv*xv.y;
            acc[j].z += wv*xv.z; acc[j].w += wv*xv.w;
        }
    }
    #pragma unroll
    for (int j = 0; j < 20; ++j) {
        const int o = og*20 + j;
        const float a_ = (o < 48) ? af : at;
        float4 v = acc[j];
        v.x = v.x >= 0.f ? v.x : a_*v.x;
        v.y = v.y >= 0.f ? v.y : a_*v.y;
        v.z = v.z >= 0.f ? v.z : a_*v.z;
        v.w = v.w >= 0.f ? v.w : a_*v.w;
        float* dst = (o < 48) ? (fq + ((long)b*48 + o)*FT + n0)
                              : (tq + ((long)b*32 + (o-48))*FT + n0);
        *(float4*)dst = v;
    }
}

// ---------------------------------------------------------------------------
// Stage 2: frequency attention, MFMA flash-style. One block per (b,t),
// 256 threads (4 waves), each wave owns f-tiles {w, w+4, ...}.
// S^T = K^T*Q via mfma_f32_16x16x16_f16 (A=K^T[y][c], B=Q^T[f][c] frags);
// P^T exits in B-operand layout -> feeds O[c][f] += V[c][y]*P^T[y][f].
// LDS strides: KT/QT rows of 20 f16 (10 words, conflict-free frag reads),
// Vs rows of 280 f16 (140 words -> 2-way, free).
// ---------------------------------------------------------------------------
__global__ __launch_bounds__(256) void fattn_kernel(
    const float* __restrict__ fq, float* __restrict__ fo)
{
    __shared__ half_t KT[272*20];   // [y][c]
    __shared__ half_t QT[272*20];   // [f][c], pre-scaled by 0.25
    __shared__ half_t Vs[16*280];   // [c][y]
    const int tid = threadIdx.x;
    const int b = blockIdx.x / TD, t = blockIdx.x % TD;
    const float* base = fq + (long)b*48*FT + t;
    for (int idx = tid; idx < 16*272; idx += 256) {
        const int c = idx / 272, f = idx - c*272;
        float qv = 0.f, kv = 0.f, vv = 0.f;
        if (f < FD) {
            const long off = (long)f*TD;
            qv = base[(long)(3*c  )*FT + off]*0.25f;
            kv = base[(long)(3*c+1)*FT + off];
            vv = base[(long)(3*c+2)*FT + off];
        }
        QT[f*20 + c] = (half_t)qv;
        KT[f*20 + c] = (half_t)kv;
        Vs[c*280 + f] = (half_t)vv;
    }
    __syncthreads();
    const int w = tid >> 6, lane = tid & 63;
    const int lmod = lane & 15, ldiv = lane >> 4;
    for (int ft = w; ft < 17; ft += 4) {
        const int f0 = 16*ft;
        const half4 qb = *(const half4*)&QT[(f0+lmod)*20 + 4*ldiv];
        f32x4 o = {0.f,0.f,0.f,0.f};
        float m = NEGINF, l = 0.f;
        for (int yt = 0; yt < 17; ++yt) {
            const int y0 = 16*yt;
            const half4 ka = *(const half4*)&KT[(y0+lmod)*20 + 4*ldiv];
            f32x4 s = __builtin_amdgcn_mfma_f32_16x16x16f16(
                ka, qb, (f32x4){0.f,0.f,0.f,0.f}, 0, 0, 0);
            if (yt == 16) {                      // mask rows y >= FD
                #pragma unroll
                for (int r = 0; r < 4; ++r)
                    if (y0 + 4*ldiv + r >= FD) s[r] = NEGINF;
            }
            float mt = fmaxf(fmaxf(s[0],s[1]), fmaxf(s[2],s[3]));
            mt = fmaxf(mt, __shfl_xor(mt, 16, 64));
            mt = fmaxf(mt, __shfl_xor(mt, 32, 64));
            const float mn = fmaxf(m, mt);
            const float alpha = __expf(m - mn);
            half4 pb; float ps = 0.f;
            #pragma unroll
            for (int r = 0; r < 4; ++r) {
                const float p = __expf(s[r] - mn);
                pb[r] = (half_t)p; ps += p;
            }
            ps += __shfl_xor(ps, 16, 64);
            ps += __shfl_xor(ps, 32, 64);
            l = l*alpha + ps;  m = mn;
            o[0] *= alpha; o[1] *= alpha; o[2] *= alpha; o[3] *= alpha;
            const half4 va = *(const half4*)&Vs[lmod*280 + y0 + 4*ldiv];
            o = __builtin_amdgcn_mfma_f32_16x16x16f16(va, pb, o, 0, 0, 0);
        }
        const float inv = 1.f/l;
        const int f = f0 + lmod;
        if (f < FD) {
            #pragma unroll
            for (int r = 0; r < 4; ++r) {
                const int c = 4*ldiv + r;
                fo[((long)(b*16 + c)*FD + f)*TD + t] = o[r]*inv;
            }
        }
    }
}

// ---------------------------------------------------------------------------
// Stage 3: causal time attention, MFMA flash-style. One block per (b,f),
// 512 threads (8 waves); wave w owns t-tiles {w, 15-w, 16+w, 31-w}
// (66 tile-pairs each -> perfectly balanced). Dynamic LDS 57.6 KB.
// ---------------------------------------------------------------------------
__global__ __launch_bounds__(512) void tattn_kernel(
    const float* __restrict__ tq, const float* __restrict__ fo,
    float* __restrict__ tout)
{
    extern __shared__ half_t lds[];
    half_t* KT  = lds;              // [512 y][20]
    half_t* QT  = KT + 512*20;      // [512 t][20], pre-scaled by 0.25
    half_t* FOs = QT + 512*20;      // [16 c][520]
    const int tid = threadIdx.x;
    const int b = blockIdx.x / FD, f = blockIdx.x % FD;
    const float* qbase = tq + (long)b*32*FT + (long)f*TD;
    const float* fbase = fo + (long)b*16*FT + (long)f*TD;
    for (int idx = tid; idx < 16*512; idx += 512) {
        const int c = idx >> 9, y = idx & 511;
        float qv = 0.f, kv = 0.f, fv = 0.f;
        if (y < TD) {
            qv = qbase[(long)(2*c  )*FT + y]*0.25f;
            kv = qbase[(long)(2*c+1)*FT + y];
            fv = fbase[(long)c*FT + y];
        }
        QT[y*20 + c] = (half_t)qv;
        KT[y*20 + c] = (half_t)kv;
        FOs[c*520 + y] = (half_t)fv;
    }
    __syncthreads();
    const int w = tid >> 6, lane = tid & 63;
    const int lmod = lane & 15, ldiv = lane >> 4;
    const int tts[4] = {w, 15-w, 16+w, 31-w};
    #pragma unroll
    for (int i = 0; i < 4; ++i) {
        const int tt = tts[i];
        const int t0 = 16*tt;
        const half4 qb = *(const half4*)&QT[(t0+lmod)*20 + 4*ldiv];
        f32x4 o = {0.f,0.f,0.f,0.f};
        float m = NEGINF, l = 0.f;
        for (int yt = 0; yt <= tt; ++yt) {
            const half4 ka = *(const half4*)&KT[(16*yt+lmod)*20 + 4*ldiv];
            f32x4 s = __builtin_amdgcn_mfma_f32_16x16x16f16(
                ka, qb, (f32x4){0.f,0.f,0.f,0.f}, 0, 0, 0);
            if (yt == tt) {                      // diagonal tile: mask y > t
                #pragma unroll
                for (int r = 0; r < 4; ++r)
                    if (4*ldiv + r > lmod) s[r] = NEGINF;
            }
            float mt = fmaxf(fmaxf(s[0],s[1]), fmaxf(s[2],s[3]));
            mt = fmaxf(mt, __shfl_xor(mt, 16, 64));
            mt = fmaxf(mt, __shfl_xor(mt, 32, 64));
            const float mn = fmaxf(m, mt);
            const float alpha = __expf(m - mn);
            half4 pb; float ps = 0.f;
            #pragma unroll
            for (int r = 0; r < 4; ++r) {
                const float p = __expf(s[r] - mn);
                pb[r] = (half_t)p; ps += p;
            }
            ps += __shfl_xor(ps, 16, 64);
            ps += __shfl_xor(ps, 32, 64);
            l = l*alpha + ps;  m = mn;
            o[0] *= alpha; o[1] *= alpha; o[2] *= alpha; o[3] *= alpha;
            const half4 fa4 = *(const half4*)&FOs[lmod*520 + 16*yt + 4*ldiv];
            o = __builtin_amdgcn_mfma_f32_16x16x16f16(fa4, pb, o, 0, 0, 0);
        }
        const float inv = 1.f/l;
        const int t = t0 + lmod;
        if (t < TD) {
            #pragma unroll
            for (int r = 0; r < 4; ++r) {
                const int c = 4*ldiv + r;
                tout[((long)(b*16 + c)*FD + f)*TD + t] = o[r]*inv;
            }
        }
    }
}

// ---------------------------------------------------------------------------
// Stage 4: proj 16->64 + BN + PReLU + residual. (unchanged from round 3)
// ---------------------------------------------------------------------------
__global__ __launch_bounds__(256) void proj_kernel(
    const float* __restrict__ tout, const float* __restrict__ x,
    const float* __restrict__ pw, const float* __restrict__ pb_,
    const float* __restrict__ pg, const float* __restrict__ pbe,
    const float* __restrict__ pm, const float* __restrict__ pv_,
    const float* __restrict__ pa,
    float* __restrict__ out)
{
    __shared__ float PW[64*16];
    __shared__ float PB[64];
    const int tid = threadIdx.x;
    for (int idx = tid; idx < 64*16; idx += 256) {
        const int o = idx >> 4;
        PW[idx] = pw[idx]*(pg[o]*rsqrtf(pv_[o]+EPS));
    }
    if (tid < 64) {
        const int o = tid;
        PB[o] = (pb_[o]-pm[o])*(pg[o]*rsqrtf(pv_[o]+EPS)) + pbe[o];
    }
    __syncthreads();
    const float ap = pa[0];
    const int og = tid >> 6, lane = tid & 63;
    const int b  = blockIdx.x / 502;
    const int nb = blockIdx.x % 502;
    const long n0 = (long)nb*256 + lane*4;
    if (n0 >= FT) return;
    float4 acc[16];
    #pragma unroll
    for (int j = 0; j < 16; ++j) {
        const float bv = PB[og*16+j];
        acc[j] = make_float4(bv, bv, bv, bv);
    }
    const float* tb = tout + (long)b*16*FT + n0;
    #pragma unroll
    for (int cc = 0; cc < 16; ++cc) {
        const float4 tv = *(const float4*)(tb + (long)cc*FT);
        #pragma unroll
        for (int j = 0; j < 16; ++j) {
            const float wv = PW[(og*16+j)*16 + cc];
            acc[j].x += wv*tv.x; acc[j].y += wv*tv.y;
            acc[j].z += wv*tv.z; acc[j].w += wv*tv.w;
        }
    }
    #pragma unroll
    for (int j = 0; j < 16; ++j) {
        const int o = og*16 + j;
        float4 v = acc[j];
        v.x = v.x >= 0.f ? v.x : ap*v.x;
        v.y = v.y >= 0.f ? v.y : ap*v.y;
        v.z = v.z >= 0.f ? v.z : ap*v.z;
        v.w = v.w >= 0.f ? v.w : ap*v.w;
        const long gi = (long)(b*64 + o)*FT + n0;
        const float4 xv = *(const float4*)(x + gi);
        v.x += xv.x; v.y += xv.y; v.z += xv.z; v.w += xv.w;
        *(float4*)(out + gi) = v;
    }
}

extern "C" void kernel_launch(void* const* d_in, const int* in_sizes, int n_in,
                              void* d_out, int out_size, void* d_ws, size_t ws_size,
                              hipStream_t stream)
{
    const float* x     = (const float*)d_in[0];
    const float* fw    = (const float*)d_in[1];
    const float* fb_   = (const float*)d_in[2];
    const float* fg    = (const float*)d_in[3];
    const float* fbe   = (const float*)d_in[4];
    const float* fm    = (const float*)d_in[5];
    const float* fv_   = (const float*)d_in[6];
    const float* fa    = (const float*)d_in[7];
    const float* tw    = (const float*)d_in[8];
    const float* tb_   = (const float*)d_in[9];
    const float* tg    = (const float*)d_in[10];
    const float* tbe   = (const float*)d_in[11];
    const float* tm    = (const float*)d_in[12];
    const float* tv_   = (const float*)d_in[13];
    const float* ta    = (const float*)d_in[14];
    const float* pw    = (const float*)d_in[15];
    const float* pb_   = (const float*)d_in[16];
    const float* pg    = (const float*)d_in[17];
    const float* pbe   = (const float*)d_in[18];
    const float* pm    = (const float*)d_in[19];
    const float* pv_   = (const float*)d_in[20];
    const float* pa    = (const float*)d_in[21];
    float* out = (float*)d_out;

    float* fq   = (float*)d_ws;                    // [2][48][257][500]
    float* fo   = fq + (long)BB*48*FT;             // [2][16][257][500]
    float* tq   = fo + (long)BB*16*FT;             // [2][32][257][500]
    float* tout = fq;                              // alias: fq dead after fattn
    const size_t need = ((size_t)BB*(48+16+32)*FT)*sizeof(float);
    if (ws_size < need) return;

    stage1_kernel<<<dim3(BB*502), dim3(256), 0, stream>>>(
        x, fw, fb_, fg, fbe, fm, fv_, fa, tw, tb_, tg, tbe, tm, tv_, ta, fq, tq);

    fattn_kernel<<<dim3(BB*TD), dim3(256), 0, stream>>>(fq, fo);

    const int tlds = (512*20*2 + 16*520)*(int)sizeof(half_t);  // 57,600 B
    hipFuncSetAttribute(reinterpret_cast<const void*>(tattn_kernel),
                        hipFuncAttributeMaxDynamicSharedMemorySize, tlds);
    tattn_kernel<<<dim3(BB*FD), dim3(512), tlds, stream>>>(tq, fo, tout);

    proj_kernel<<<dim3(BB*502), dim3(256), 0, stream>>>(
        tout, x, pw, pb_, pg, pbe, pm, pv_, pa, out);
}

// Round 5
// 346.678 us; speedup vs baseline: 7.0464x; 1.2340x over previous
//
#include <hip/hip_runtime.h>

#define BB 2
#define CIN 64
#define FD 257
#define TD 500
#define FT (FD*TD)      // 128500
#define EPS 1e-5f
#define NEGINF (-3.0e38f)
#define FDP 260         // fqT padded row length (halves, 8B-aligned rows)
#define FQT_PLANE (TD*FDP)   // 130000 halves per (b,channel) plane

typedef _Float16 half_t;
typedef half_t half4 __attribute__((ext_vector_type(4)));
typedef float  f32x4 __attribute__((ext_vector_type(4)));

// ---------------------------------------------------------------------------
// Stage 1: fused fqkv (48ch) + tqk (32ch) 1x1 conv + folded BN + PReLU.
// Outputs f16 (both consumers convert to f16 anyway).
// ---------------------------------------------------------------------------
__global__ __launch_bounds__(256) void stage1_kernel(
    const float* __restrict__ x,
    const float* __restrict__ fw, const float* __restrict__ fb_,
    const float* __restrict__ fg, const float* __restrict__ fbe,
    const float* __restrict__ fm, const float* __restrict__ fv_,
    const float* __restrict__ fa,
    const float* __restrict__ tw, const float* __restrict__ tb_,
    const float* __restrict__ tg, const float* __restrict__ tbe,
    const float* __restrict__ tm, const float* __restrict__ tv_,
    const float* __restrict__ ta,
    half_t* __restrict__ fq, half_t* __restrict__ tq)
{
    __shared__ float Wl[80*64];
    __shared__ float Bl[80];
    const int tid = threadIdx.x;
    for (int idx = tid; idx < 80*64; idx += 256) {
        const int o = idx >> 6, i = idx & 63;
        float sc, wv;
        if (o < 48) { sc = fg[o]*rsqrtf(fv_[o]+EPS); wv = fw[o*64+i]; }
        else { const int o2 = o-48; sc = tg[o2]*rsqrtf(tv_[o2]+EPS); wv = tw[o2*64+i]; }
        Wl[idx] = wv*sc;
    }
    if (tid < 80) {
        const int o = tid;
        if (o < 48) Bl[o] = (fb_[o]-fm[o])*(fg[o]*rsqrtf(fv_[o]+EPS)) + fbe[o];
        else { const int o2 = o-48; Bl[o] = (tb_[o2]-tm[o2])*(tg[o2]*rsqrtf(tv_[o2]+EPS)) + tbe[o2]; }
    }
    __syncthreads();
    const float af = fa[0], at = ta[0];
    const int og = tid >> 6, lane = tid & 63;
    const int b  = blockIdx.x / 502;
    const int nb = blockIdx.x % 502;
    const long n0 = (long)nb*256 + lane*4;
    if (n0 >= FT) return;

    float4 acc[20];
    #pragma unroll
    for (int j = 0; j < 20; ++j) {
        const float bv = Bl[og*20+j];
        acc[j] = make_float4(bv, bv, bv, bv);
    }
    const float* xb = x + (long)b*CIN*FT + n0;
    #pragma unroll 4
    for (int i = 0; i < 64; ++i) {
        const float4 xv = *(const float4*)(xb + (long)i*FT);
        #pragma unroll
        for (int j = 0; j < 20; ++j) {
            const float wv = Wl[(og*20+j)*64 + i];
            acc[j].x += wv*xv.x; acc[j].y += wv*xv.y;
            acc[j].z += wv*xv.z; acc[j].w += wv*xv.w;
        }
    }
    #pragma unroll
    for (int j = 0; j < 20; ++j) {
        const int o = og*20 + j;
        const float a_ = (o < 48) ? af : at;
        float4 v = acc[j];
        v.x = v.x >= 0.f ? v.x : a_*v.x;
        v.y = v.y >= 0.f ? v.y : a_*v.y;
        v.z = v.z >= 0.f ? v.z : a_*v.z;
        v.w = v.w >= 0.f ? v.w : a_*v.w;
        half4 hv;
        hv[0] = (half_t)v.x; hv[1] = (half_t)v.y;
        hv[2] = (half_t)v.z; hv[3] = (half_t)v.w;
        half_t* dst = (o < 48) ? (fq + ((long)b*48 + o)*FT + n0)
                               : (tq + ((long)b*32 + (o-48))*FT + n0);
        *(half4*)dst = hv;
    }
}

// ---------------------------------------------------------------------------
// Transpose (f16->f16): src[plane][R][C] -> dst[plane][C][RP], pad r in
// [R,RP) zeroed. 64x64 LDS tile, coalesced both sides.
// ---------------------------------------------------------------------------
__global__ __launch_bounds__(256) void transpose_h2h_kernel(
    const half_t* __restrict__ src, half_t* __restrict__ dst,
    int R, int C, int RP)
{
    __shared__ half_t tile[64][66];
    const int plane = blockIdx.x;
    const int rb = blockIdx.y*64, cb = blockIdx.z*64;
    const half_t* s = src + (long)plane*R*C;
    half_t* d = dst + (long)plane*C*RP;
    const int tx = threadIdx.x & 63, ty = threadIdx.x >> 6;
    #pragma unroll
    for (int k = 0; k < 16; ++k) {
        const int r = rb + ty + 4*k, c = cb + tx;
        half_t v = (half_t)0.f;
        if (r < R && c < C) v = s[(long)r*C + c];
        tile[tx][ty + 4*k] = v;
    }
    __syncthreads();
    #pragma unroll
    for (int k = 0; k < 16; ++k) {
        const int c = cb + ty + 4*k, r = rb + tx;
        if (c < C && r < RP) d[(long)c*RP + r] = tile[ty + 4*k][tx];
    }
}

// f32 -> f16 variant (for foT -> fo)
__global__ __launch_bounds__(256) void transpose_f2h_kernel(
    const float* __restrict__ src, half_t* __restrict__ dst,
    int R, int C, int RP)
{
    __shared__ half_t tile[64][66];
    const int plane = blockIdx.x;
    const int rb = blockIdx.y*64, cb = blockIdx.z*64;
    const float* s = src + (long)plane*R*C;
    half_t* d = dst + (long)plane*C*RP;
    const int tx = threadIdx.x & 63, ty = threadIdx.x >> 6;
    #pragma unroll
    for (int k = 0; k < 16; ++k) {
        const int r = rb + ty + 4*k, c = cb + tx;
        half_t v = (half_t)0.f;
        if (r < R && c < C) v = (half_t)s[(long)r*C + c];
        tile[tx][ty + 4*k] = v;
    }
    __syncthreads();
    #pragma unroll
    for (int k = 0; k < 16; ++k) {
        const int c = cb + ty + 4*k, r = rb + tx;
        if (c < C && r < RP) d[(long)c*RP + r] = tile[ty + 4*k][tx];
    }
}

// ---------------------------------------------------------------------------
// Stage 2: frequency attention, MFMA flash-style. One block per (b,t),
// 256 threads (4 waves). Reads fqT[b][48][t][FDP] (coalesced half4 rows),
// writes foT[b][16][t][FD] f32 (coalesced dwords). Compute core = round 4.
// ---------------------------------------------------------------------------
__global__ __launch_bounds__(256) void fattn_kernel(
    const half_t* __restrict__ fqT, float* __restrict__ foT)
{
    __shared__ half_t KT[272*20];   // [y][c]
    __shared__ half_t QT[272*20];   // [f][c], pre-scaled by 0.25
    __shared__ half_t Vs[16*280];   // [c][y]
    const int tid = threadIdx.x;
    const int b = blockIdx.x / TD, t = blockIdx.x % TD;
    const half_t* base = fqT + (long)b*48*FQT_PLANE + (long)t*FDP;
    for (int s = tid; s < 48*68; s += 256) {
        const int c3 = s / 68, j = s - c3*68;
        const int f0 = 4*j;
        half4 v = {(half_t)0.f,(half_t)0.f,(half_t)0.f,(half_t)0.f};
        if (f0 < FDP) v = *(const half4*)(base + (long)c3*FQT_PLANE + f0);
        const int c = c3 / 3, wh = c3 - 3*c;   // q=3c, k=3c+1, v=3c+2
        if (wh == 0) {
            #pragma unroll
            for (int e = 0; e < 4; ++e) QT[(f0+e)*20 + c] = v[e]*(half_t)0.25f;
        } else if (wh == 1) {
            #pragma unroll
            for (int e = 0; e < 4; ++e) KT[(f0+e)*20 + c] = v[e];
        } else {
            *(half4*)&Vs[c*280 + f0] = v;
        }
    }
    __syncthreads();
    const int w = tid >> 6, lane = tid & 63;
    const int lmod = lane & 15, ldiv = lane >> 4;
    for (int ft = w; ft < 17; ft += 4) {
        const int f0 = 16*ft;
        const half4 qb = *(const half4*)&QT[(f0+lmod)*20 + 4*ldiv];
        f32x4 o = {0.f,0.f,0.f,0.f};
        float m = NEGINF, l = 0.f;
        for (int yt = 0; yt < 17; ++yt) {
            const int y0 = 16*yt;
            const half4 ka = *(const half4*)&KT[(y0+lmod)*20 + 4*ldiv];
            f32x4 s = __builtin_amdgcn_mfma_f32_16x16x16f16(
                ka, qb, (f32x4){0.f,0.f,0.f,0.f}, 0, 0, 0);
            if (yt == 16) {                      // mask rows y >= FD
                #pragma unroll
                for (int r = 0; r < 4; ++r)
                    if (y0 + 4*ldiv + r >= FD) s[r] = NEGINF;
            }
            float mt = fmaxf(fmaxf(s[0],s[1]), fmaxf(s[2],s[3]));
            mt = fmaxf(mt, __shfl_xor(mt, 16, 64));
            mt = fmaxf(mt, __shfl_xor(mt, 32, 64));
            const float mn = fmaxf(m, mt);
            const float alpha = __expf(m - mn);
            half4 pb; float ps = 0.f;
            #pragma unroll
            for (int r = 0; r < 4; ++r) {
                const float p = __expf(s[r] - mn);
                pb[r] = (half_t)p; ps += p;
            }
            ps += __shfl_xor(ps, 16, 64);
            ps += __shfl_xor(ps, 32, 64);
            l = l*alpha + ps;  m = mn;
            o[0] *= alpha; o[1] *= alpha; o[2] *= alpha; o[3] *= alpha;
            const half4 va = *(const half4*)&Vs[lmod*280 + y0 + 4*ldiv];
            o = __builtin_amdgcn_mfma_f32_16x16x16f16(va, pb, o, 0, 0, 0);
        }
        const float inv = 1.f/l;
        const int f = f0 + lmod;
        if (f < FD) {
            #pragma unroll
            for (int r = 0; r < 4; ++r) {
                const int c = 4*ldiv + r;
                foT[((long)(b*16 + c)*TD + t)*FD + f] = o[r]*inv;
            }
        }
    }
}

// ---------------------------------------------------------------------------
// Stage 3: causal time attention, MFMA flash-style. One block per (b,f),
// 512 threads (8 waves). Inputs tq/fo are f16 natural layout (coalesced).
// ---------------------------------------------------------------------------
__global__ __launch_bounds__(512) void tattn_kernel(
    const half_t* __restrict__ tq, const half_t* __restrict__ fo,
    float* __restrict__ tout)
{
    extern __shared__ half_t lds[];
    half_t* KT  = lds;              // [512 y][20]
    half_t* QT  = KT + 512*20;      // [512 t][20], pre-scaled by 0.25
    half_t* FOs = QT + 512*20;      // [16 c][520]
    const int tid = threadIdx.x;
    const int b = blockIdx.x / FD, f = blockIdx.x % FD;
    const half_t* qbase = tq + (long)b*32*FT + (long)f*TD;
    const half_t* fbase = fo + (long)b*16*FT + (long)f*TD;
    for (int idx = tid; idx < 16*512; idx += 512) {
        const int c = idx >> 9, y = idx & 511;
        half_t qv = (half_t)0.f, kv = (half_t)0.f, fv = (half_t)0.f;
        if (y < TD) {
            qv = qbase[(long)(2*c  )*FT + y]*(half_t)0.25f;
            kv = qbase[(long)(2*c+1)*FT + y];
            fv = fbase[(long)c*FT + y];
        }
        QT[y*20 + c] = qv;
        KT[y*20 + c] = kv;
        FOs[c*520 + y] = fv;
    }
    __syncthreads();
    const int w = tid >> 6, lane = tid & 63;
    const int lmod = lane & 15, ldiv = lane >> 4;
    const int tts[4] = {w, 15-w, 16+w, 31-w};
    #pragma unroll
    for (int i = 0; i < 4; ++i) {
        const int tt = tts[i];
        const int t0 = 16*tt;
        const half4 qb = *(const half4*)&QT[(t0+lmod)*20 + 4*ldiv];
        f32x4 o = {0.f,0.f,0.f,0.f};
        float m = NEGINF, l = 0.f;
        for (int yt = 0; yt <= tt; ++yt) {
            const half4 ka = *(const half4*)&KT[(16*yt+lmod)*20 + 4*ldiv];
            f32x4 s = __builtin_amdgcn_mfma_f32_16x16x16f16(
                ka, qb, (f32x4){0.f,0.f,0.f,0.f}, 0, 0, 0);
            if (yt == tt) {                      // diagonal tile: mask y > t
                #pragma unroll
                for (int r = 0; r < 4; ++r)
                    if (4*ldiv + r > lmod) s[r] = NEGINF;
            }
            float mt = fmaxf(fmaxf(s[0],s[1]), fmaxf(s[2],s[3]));
            mt = fmaxf(mt, __shfl_xor(mt, 16, 64));
            mt = fmaxf(mt, __shfl_xor(mt, 32, 64));
            const float mn = fmaxf(m, mt);
            const float alpha = __expf(m - mn);
            half4 pb; float ps = 0.f;
            #pragma unroll
            for (int r = 0; r < 4; ++r) {
                const float p = __expf(s[r] - mn);
                pb[r] = (half_t)p; ps += p;
            }
            ps += __shfl_xor(ps, 16, 64);
            ps += __shfl_xor(ps, 32, 64);
            l = l*alpha + ps;  m = mn;
            o[0] *= alpha; o[1] *= alpha; o[2] *= alpha; o[3] *= alpha;
            const half4 fa4 = *(const half4*)&FOs[lmod*520 + 16*yt + 4*ldiv];
            o = __builtin_amdgcn_mfma_f32_16x16x16f16(fa4, pb, o, 0, 0, 0);
        }
        const float inv = 1.f/l;
        const int t = t0 + lmod;
        if (t < TD) {
            #pragma unroll
            for (int r = 0; r < 4; ++r) {
                const int c = 4*ldiv + r;
                tout[((long)(b*16 + c)*FD + f)*TD + t] = o[r]*inv;
            }
        }
    }
}

// ---------------------------------------------------------------------------
// Stage 4: proj 16->64 + BN + PReLU + residual.
// ---------------------------------------------------------------------------
__global__ __launch_bounds__(256) void proj_kernel(
    const float* __restrict__ tout, const float* __restrict__ x,
    const float* __restrict__ pw, const float* __restrict__ pb_,
    const float* __restrict__ pg, const float* __restrict__ pbe,
    const float* __restrict__ pm, const float* __restrict__ pv_,
    const float* __restrict__ pa,
    float* __restrict__ out)
{
    __shared__ float PW[64*16];
    __shared__ float PB[64];
    const int tid = threadIdx.x;
    for (int idx = tid; idx < 64*16; idx += 256) {
        const int o = idx >> 4;
        PW[idx] = pw[idx]*(pg[o]*rsqrtf(pv_[o]+EPS));
    }
    if (tid < 64) {
        const int o = tid;
        PB[o] = (pb_[o]-pm[o])*(pg[o]*rsqrtf(pv_[o]+EPS)) + pbe[o];
    }
    __syncthreads();
    const float ap = pa[0];
    const int og = tid >> 6, lane = tid & 63;
    const int b  = blockIdx.x / 502;
    const int nb = blockIdx.x % 502;
    const long n0 = (long)nb*256 + lane*4;
    if (n0 >= FT) return;
    float4 acc[16];
    #pragma unroll
    for (int j = 0; j < 16; ++j) {
        const float bv = PB[og*16+j];
        acc[j] = make_float4(bv, bv, bv, bv);
    }
    const float* tb = tout + (long)b*16*FT + n0;
    #pragma unroll
    for (int cc = 0; cc < 16; ++cc) {
        const float4 tv = *(const float4*)(tb + (long)cc*FT);
        #pragma unroll
        for (int j = 0; j < 16; ++j) {
            const float wv = PW[(og*16+j)*16 + cc];
            acc[j].x += wv*tv.x; acc[j].y += wv*tv.y;
            acc[j].z += wv*tv.z; acc[j].w += wv*tv.w;
        }
    }
    #pragma unroll
    for (int j = 0; j < 16; ++j) {
        const int o = og*16 + j;
        float4 v = acc[j];
        v.x = v.x >= 0.f ? v.x : ap*v.x;
        v.y = v.y >= 0.f ? v.y : ap*v.y;
        v.z = v.z >= 0.f ? v.z : ap*v.z;
        v.w = v.w >= 0.f ? v.w : ap*v.w;
        const long gi = (long)(b*64 + o)*FT + n0;
        const float4 xv = *(const float4*)(x + gi);
        v.x += xv.x; v.y += xv.y; v.z += xv.z; v.w += xv.w;
        *(float4*)(out + gi) = v;
    }
}

extern "C" void kernel_launch(void* const* d_in, const int* in_sizes, int n_in,
                              void* d_out, int out_size, void* d_ws, size_t ws_size,
                              hipStream_t stream)
{
    const float* x     = (const float*)d_in[0];
    const float* fw    = (const float*)d_in[1];
    const float* fb_   = (const float*)d_in[2];
    const float* fg    = (const float*)d_in[3];
    const float* fbe   = (const float*)d_in[4];
    const float* fm    = (const float*)d_in[5];
    const float* fv_   = (const float*)d_in[6];
    const float* fa    = (const float*)d_in[7];
    const float* tw    = (const float*)d_in[8];
    const float* tb_   = (const float*)d_in[9];
    const float* tg    = (const float*)d_in[10];
    const float* tbe   = (const float*)d_in[11];
    const float* tm    = (const float*)d_in[12];
    const float* tv_   = (const float*)d_in[13];
    const float* ta    = (const float*)d_in[14];
    const float* pw    = (const float*)d_in[15];
    const float* pb_   = (const float*)d_in[16];
    const float* pg    = (const float*)d_in[17];
    const float* pbe   = (const float*)d_in[18];
    const float* pm    = (const float*)d_in[19];
    const float* pv_   = (const float*)d_in[20];
    const float* pa    = (const float*)d_in[21];
    float* out = (float*)d_out;

    // Workspace layout (bytes):
    //  A: fqh  f16 [2][48][FT]           24,672,000   (foT f32 [2][16][FT]=16,448,000 aliases after T1)
    //  B: foh  f16 [2][16][FT]            8,224,000
    //  C: tqh  f16 [2][32][FT]           16,448,000
    //  D: fqTh f16 [96][FQT_PLANE]       24,960,000   (tout f32 [2][16][FT] aliases after fattn)
    char* base = (char*)d_ws;
    const size_t szA = (size_t)BB*48*FT*sizeof(half_t);
    const size_t szB = (size_t)BB*16*FT*sizeof(half_t);
    const size_t szC = (size_t)BB*32*FT*sizeof(half_t);
    const size_t szD = (size_t)96*FQT_PLANE*sizeof(half_t);
    const size_t need = szA + szB + szC + szD;   // 74,304,000
    if (ws_size < need) return;
    half_t* fqh  = (half_t*)base;
    float*  foT  = (float*)base;                 // alias A
    half_t* foh  = (half_t*)(base + szA);
    half_t* tqh  = (half_t*)(base + szA + szB);
    half_t* fqTh = (half_t*)(base + szA + szB + szC);
    float*  tout = (float*)(base + szA + szB + szC);  // alias D

    stage1_kernel<<<dim3(BB*502), dim3(256), 0, stream>>>(
        x, fw, fb_, fg, fbe, fm, fv_, fa, tw, tb_, tg, tbe, tm, tv_, ta, fqh, tqh);

    // T1: fq[b][c][f][t] -> fqT[b][c][t][f(pad 260)]
    transpose_h2h_kernel<<<dim3(BB*48, 5, 8), dim3(256), 0, stream>>>(
        fqh, fqTh, FD, TD, FDP);

    fattn_kernel<<<dim3(BB*TD), dim3(256), 0, stream>>>(fqTh, foT);

    // T2: foT[b][c][t][f] (f32) -> fo[b][c][f][t] (f16)
    transpose_f2h_kernel<<<dim3(BB*16, 8, 5), dim3(256), 0, stream>>>(
        foT, foh, TD, FD, TD);

    const int tlds = (512*20*2 + 16*520)*(int)sizeof(half_t);  // 57,600 B
    hipFuncSetAttribute(reinterpret_cast<const void*>(tattn_kernel),
                        hipFuncAttributeMaxDynamicSharedMemorySize, tlds);
    tattn_kernel<<<dim3(BB*FD), dim3(512), tlds, stream>>>(tqh, foh, tout);

    proj_kernel<<<dim3(BB*502), dim3(256), 0, stream>>>(
        tout, x, pw, pb_, pg, pbe, pm, pv_, pa, out);
}